// Round 4
// baseline (102.852 us; speedup 1.0000x reference)
//

#include <hip/hip_runtime.h>

// RadiusInteractionGraph: B=128 molecules x 512 atoms, K=32 NN, cutoff 10.
// d_out is FLOAT32: [E] src ++ [E] dst ++ [E] weight, E = 128*512*32.
//
// R25 = R24 (all-VALU exchanges, dual-half epilogue, 48.8us, VGPR=40) with
// two EXACT VALU op-count cuts. R22-R24 post-mortems: scheduling-only
// changes are exhausted (VALUBusy 78%, issue-time ~38us of 48.8); cut ops.
//  (1) Packed-FP32 key build: v_pk_mul_f32/v_pk_add_f32 do 2 IEEE-exact f32
//      ops per VALU slot. Rows A,B share pj -> pack {A,B} per component:
//      dot+d2 for both rows = 8 pk + 4 bcast movs (was 18 scalar). Rounding
//      bit-identical per lane-half; s - 2*dot == s + (-2)*dot exactly (RN is
//      sign-symmetric).
//  (2) Early-exit rank search: correctness needs ONLY a downward-closed
//      window with 32 <= count(<hi) <= 64 (sort of any such window gives the
//      identical top-32). So when a REJECTED candidate C has count in
//      [32,64], set hi=C and stop that row's search (saves 2-4 rounds of 8
//      v_cmps typically). Rows that never hit the band follow the old path
//      (incl. W>64 exact-refine fallback) -> unconditional correctness.
// Selection semantics bit-identical: key=(d2_hi23|j) lex == lax.top_k stable
// order; exact __f*_rn np arithmetic; sentinel 0x7F800000|j -> pad self-edge.

constexpr int EDGES = 128 * 512 * 32;   // 2097152

typedef float f32x2 __attribute__((ext_vector_type(2)));

static __device__ __forceinline__ f32x2 pk_mul(f32x2 a, f32x2 b) {
    f32x2 d;
    asm("v_pk_mul_f32 %0, %1, %2" : "=v"(d) : "v"(a), "v"(b));
    return d;
}
static __device__ __forceinline__ f32x2 pk_add(f32x2 a, f32x2 b) {
    f32x2 d;
    asm("v_pk_add_f32 %0, %1, %2" : "=v"(d) : "v"(a), "v"(b));
    return d;
}

static __device__ __forceinline__ unsigned umin2(unsigned a, unsigned b) {
    return a < b ? a : b;
}
static __device__ __forceinline__ unsigned umax2(unsigned a, unsigned b) {
    return a > b ? a : b;
}

static __device__ __forceinline__ unsigned mbcnt64(unsigned long long m) {
    return __builtin_amdgcn_mbcnt_hi(
        (unsigned)(m >> 32),
        __builtin_amdgcn_mbcnt_lo((unsigned)m, 0u));
}

static __device__ __forceinline__ unsigned count_lt(const unsigned q[8],
                                                    unsigned C) {
    unsigned cnt = 0;
#pragma unroll
    for (int c = 0; c < 8; ++c)
        cnt += (unsigned)__popcll(__ballot(q[c] < C));
    return cnt;
}

// xor-partner fetch, all-VALU (no LDS pipe). Patterns verified (R24 PASS):
//  quad_perm 0xB1 = ^1, 0x4E = ^2, 0x1B = ^3; 0x141 row_half_mirror = ^7
//  within 8; 0x128 row_ror:8 = ^8 within 16 (+8 mod 16 == ^8).
template <int J>
static __device__ __forceinline__ unsigned xpart(unsigned v, int lane) {
    if constexpr (J == 1) {
        return (unsigned)__builtin_amdgcn_update_dpp(
            (int)v, (int)v, 0xB1, 0xF, 0xF, false);
    } else if constexpr (J == 2) {
        return (unsigned)__builtin_amdgcn_update_dpp(
            (int)v, (int)v, 0x4E, 0xF, 0xF, false);
    } else if constexpr (J == 4) {
        const int t = __builtin_amdgcn_update_dpp(
            (int)v, (int)v, 0x141, 0xF, 0xF, false);   // ^7 within 8
        return (unsigned)__builtin_amdgcn_update_dpp(
            t, t, 0x1B, 0xF, 0xF, false);              // ^3 -> net ^4
    } else if constexpr (J == 8) {
        return (unsigned)__builtin_amdgcn_update_dpp(
            (int)v, (int)v, 0x128, 0xF, 0xF, false);   // row_ror:8 = ^8
    } else if constexpr (J == 16) {
#if __has_builtin(__builtin_amdgcn_permlane16_swap)
        auto r = __builtin_amdgcn_permlane16_swap((int)v, (int)v, false, false);
        return (unsigned)((lane & 16) ? r[0] : r[1]);
#else
        return (unsigned)__shfl_xor((int)v, 16, 64);
#endif
    } else {
#if __has_builtin(__builtin_amdgcn_permlane32_swap)
        auto r = __builtin_amdgcn_permlane32_swap((int)v, (int)v, false, false);
        return (unsigned)((lane & 32) ? r[0] : r[1]);
#else
        return (unsigned)__shfl_xor((int)v, 32, 64);
#endif
    }
}

template <int K, int J>
static __device__ __forceinline__ void bstep(unsigned& v, int lane) {
    const unsigned p = xpart<J>(v, lane);
    const bool keepmin = (((lane & J) == 0) == ((lane & K) == 0));
    const unsigned mn = umin2(v, p);
    const unsigned mx = umax2(v, p);
    v = keepmin ? mn : mx;
}

// full ascending bitonic sort of 64 lanes (verified formula, R19/R20)
static __device__ __forceinline__ void bitonic64(unsigned& v, int lane) {
    bstep<2, 1>(v, lane);
    bstep<4, 2>(v, lane);  bstep<4, 1>(v, lane);
    bstep<8, 4>(v, lane);  bstep<8, 2>(v, lane);  bstep<8, 1>(v, lane);
    bstep<16, 8>(v, lane); bstep<16, 4>(v, lane); bstep<16, 2>(v, lane);
    bstep<16, 1>(v, lane);
    bstep<32, 16>(v, lane); bstep<32, 8>(v, lane); bstep<32, 4>(v, lane);
    bstep<32, 2>(v, lane);  bstep<32, 1>(v, lane);
    bstep<64, 32>(v, lane); bstep<64, 16>(v, lane); bstep<64, 8>(v, lane);
    bstep<64, 4>(v, lane);  bstep<64, 2>(v, lane);  bstep<64, 1>(v, lane);
}

__global__ __launch_bounds__(256)
void RadiusInteractionGraph_73246372266582_kernel(const float* __restrict__ pos,
                                                  float* __restrict__ out) {
    __shared__ float4 atoms[512];        // x, y, z, |p|^2
    __shared__ unsigned wbuf[4][2][64];  // per-wave, per-interleaved-row

    const int tid     = threadIdx.x;
    const int b       = blockIdx.x >> 5;          // 32 blocks per molecule
    const int rowbase = (blockIdx.x & 31) * 16;   // 16 rows per block
    const int base    = b * 512;

    for (int a = tid; a < 512; a += 256) {
        float x = pos[(base + a) * 3 + 0];
        float y = pos[(base + a) * 3 + 1];
        float z = pos[(base + a) * 3 + 2];
        // np: sum(p*p) = (x*x + y*y) + z*z, sequential f32, no fma
        float sq = __fadd_rn(__fadd_rn(__fmul_rn(x, x), __fmul_rn(y, y)),
                             __fmul_rn(z, z));
        atoms[a] = make_float4(x, y, z, sq);
    }
    __syncthreads();

    const int wave = tid >> 6;
    const int lane = tid & 63;

    const f32x2 NEG2 = {-2.0f, -2.0f};

    for (int rp = 0; rp < 2; ++rp) {
        const int iA = rowbase + wave * 4 + rp * 2;
        const int iB = iA + 1;
        const float4 cA = atoms[iA];
        const float4 cB = atoms[iB];
        const f32x2 CX = {cA.x, cB.x};
        const f32x2 CY = {cA.y, cB.y};
        const f32x2 CZ = {cA.z, cB.z};
        const f32x2 CW = {cA.w, cB.w};

        // ---- build 8 UNIQUE keys per lane, rows A,B packed in pk-f32 ----
        unsigned qA[8], qB[8];
#pragma unroll
        for (int c = 0; c < 8; ++c) {
            const int j = c * 64 + lane;
            const float4 pj = atoms[j];           // one ds_read_b128, shared
            const f32x2 px = {pj.x, pj.x};
            const f32x2 py = {pj.y, pj.y};
            const f32x2 pz = {pj.z, pj.z};
            const f32x2 pw = {pj.w, pj.w};
            // np einsum order: ((xi*xj + yi*yj) + zi*zj), exact per half
            const f32x2 txx = pk_mul(CX, px);
            const f32x2 tyy = pk_mul(CY, py);
            const f32x2 sxy = pk_add(txx, tyy);
            const f32x2 tzz = pk_mul(CZ, pz);
            const f32x2 dot = pk_add(sxy, tzz);
            // d2 = (ci.w + pj.w) - 2*dot == (ci.w + pj.w) + (-2)*dot exactly
            const f32x2 sw  = pk_add(CW, pw);
            const f32x2 m2  = pk_mul(dot, NEG2);
            const f32x2 d2p = pk_add(sw, m2);
            const float d2A = fmaxf(d2p.x, 0.0f);
            const float d2B = fmaxf(d2p.y, 0.0f);
            qA[c] = ((j != iA) && (d2A <= 100.0f))
                        ? ((__float_as_uint(d2A) & 0xFFFFFE00u) | (unsigned)j)
                        : (0x7F800000u | (unsigned)j);
            qB[c] = ((j != iB) && (d2B <= 100.0f))
                        ? ((__float_as_uint(d2B) & 0xFFFFFE00u) | (unsigned)j)
                        : (0x7F800000u | (unsigned)j);
        }

        // ---- greedy MSB rank bound with EARLY EXIT (bits 30..21) ----
        // Any hi with 32 <= count(<hi) <= 64 yields the identical top-32
        // after the sort; a rejected candidate in that band IS such an hi.
        unsigned XA = 0u, XB = 0u, hiA = 0u, hiB = 0u;
        bool dA = false, dB = false;
        for (int bit = 30; bit >= 21; --bit) {
            if (!dA) {
                const unsigned C = XA | (1u << bit);
                const unsigned c = count_lt(qA, C);
                if (c < 32u)       XA = C;
                else if (c <= 64u) { hiA = C; dA = true; }
            }
            if (!dB) {
                const unsigned C = XB | (1u << bit);
                const unsigned c = count_lt(qB, C);
                if (c < 32u)       XB = C;
                else if (c <= 64u) { hiB = C; dB = true; }
            }
            if (dA && dB) break;
        }
        if (!dA) {
            hiA = XA + (1u << 21);
            const unsigned WA = count_lt(qA, hiA);
            if (WA > 64u) {   // pathological: refine exactly (R19 path)
                for (int bit = 20; bit >= 0; --bit) {
                    const unsigned C = XA | (1u << bit);
                    if (count_lt(qA, C) < 32u) XA = C;
                }
                hiA = XA + 1u;
            }
        }
        if (!dB) {
            hiB = XB + (1u << 21);
            const unsigned WB = count_lt(qB, hiB);
            if (WB > 64u) {
                for (int bit = 20; bit >= 0; --bit) {
                    const unsigned C = XB | (1u << bit);
                    if (count_lt(qB, C) < 32u) XB = C;
                }
                hiB = XB + 1u;
            }
        }

        // ---- compact both windows (ballot+mbcnt), sentinel-pad to 64 ----
        wbuf[wave][0][lane] = 0xFFFFFFFFu;
        wbuf[wave][1][lane] = 0xFFFFFFFFu;
        unsigned tA = 0, tB = 0;
#pragma unroll
        for (int c = 0; c < 8; ++c) {
            const bool sA = (qA[c] < hiA);
            const bool sB = (qB[c] < hiB);
            const unsigned long long mA = __ballot(sA);
            const unsigned long long mB = __ballot(sB);
            const unsigned oA = tA + mbcnt64(mA);
            const unsigned oB = tB + mbcnt64(mB);
            if (sA) wbuf[wave][0][oA] = qA[c];
            if (sB) wbuf[wave][1][oB] = qB[c];
            tA += (unsigned)__popcll(mA);
            tB += (unsigned)__popcll(mB);
        }

        unsigned vA = wbuf[wave][0][lane];   // per-wave LDS is in-order
        unsigned vB = wbuf[wave][1][lane];

        // ---- two interleaved bitonic sort-64s (independent, all-VALU) ----
        bitonic64(vA, lane);
        bitonic64(vB, lane);

        // ---- epilogue on BOTH halves: row A -> lanes 0..31, row B ->
        //      lanes 32..63 (one permlane32 exchange); each of the 3 stores
        //      is a contiguous 256 B wave store (rows iA,iB adjacent).
        const unsigned vBup = xpart<32>(vB, lane);
        const int half = lane >> 5;
        const int l32  = lane & 31;
        const unsigned vv = half ? vBup : vA;
        const int gi   = iA + half;               // center atom (local idx)
        const int gdst = base + gi;
        const float4 ci = half ? cB : cA;
        float w = 0.0f;
        float srcf = (float)gdst;                 // sentinel -> self-edge, w=0
        if (vv < 0x7F800000u) {
            const int j = (int)(vv & 511u);
            const float4 pj = atoms[j];
            float dot = __fadd_rn(__fadd_rn(__fmul_rn(ci.x, pj.x),
                                            __fmul_rn(ci.y, pj.y)),
                                  __fmul_rn(ci.z, pj.z));
            float d2 = __fsub_rn(__fadd_rn(ci.w, pj.w),
                                 __fmul_rn(2.0f, dot));
            d2 = fmaxf(d2, 0.0f);
            w = __fsqrt_rn(fmaxf(d2, 1e-12f));
            srcf = (float)(base + j);
        }
        const size_t eb = (size_t)gdst * 32 + (size_t)l32;
        out[eb]                     = srcf;          // src
        out[(size_t)EDGES + eb]     = (float)gdst;   // dst
        out[(size_t)EDGES * 2 + eb] = w;             // weight
    }
}

extern "C" void kernel_launch(void* const* d_in, const int* in_sizes, int n_in,
                              void* d_out, int out_size, void* d_ws, size_t ws_size,
                              hipStream_t stream) {
    (void)in_sizes; (void)n_in; (void)d_ws; (void)ws_size; (void)out_size;
    const float* pos = (const float*)d_in[0];   // [N,3] f32
    float* out       = (float*)d_out;           // [3E] f32

    RadiusInteractionGraph_73246372266582_kernel<<<dim3(4096), dim3(256), 0,
                                                   stream>>>(pos, out);
}